// Round 1
// baseline (22246.802 us; speedup 1.0000x reference)
//
#include <hip/hip_runtime.h>
#include <hip/hip_fp16.h>

typedef _Float16 f16x8 __attribute__((ext_vector_type(8)));
typedef float f32x4 __attribute__((ext_vector_type(4)));
typedef unsigned short u16;
typedef unsigned int u32;

#define T_STEPS 512
#define BATCH   512
#define DTF     0.01f

// workspace layout (bytes)
#define CTR_OFF 0
#define CTR_SZ  65536                       // 8 groups * 2048 u32 progress slots
#define WB_OFF  (CTR_OFF + CTR_SZ)
#define WB_SZ   (32*3*50*64*8*2)            // 4,915,200  combined W_h/W_p f16, B-frag layout
#define WRB_OFF (WB_OFF + WB_SZ)
#define WRB_SZ  (4*24*64*8*2)               // 98,304     W_r f16, B-frag layout
#define ST_OFF  (WRB_OFF + WRB_SZ)
#define ST_SZ   (2*8*2*64*1536*2)           // 6,291,456  state tiles [buf][g][plane][64][1536] f16
#define HP_OFF  (ST_OFF + ST_SZ)
#define HP_SZ   (8*16*4*3*64*4*2)           // 786,432    hp exchange frags
#define WS_NEED (HP_OFF + HP_SZ)

#define MFMA16(a,b,c) __builtin_amdgcn_mfma_f32_16x16x32_f16((a),(b),(c),0,0,0)

__device__ __forceinline__ u16 f2h(float f){ _Float16 h = (_Float16)f; return *reinterpret_cast<u16*>(&h); }
__device__ __forceinline__ float h2f(u16 u){ _Float16 h = *reinterpret_cast<_Float16*>(&u); return (float)h; }

__device__ __forceinline__ float ftanh(float x){
  float a = fminf(fmaxf(x, -12.f), 12.f);
  float e = __expf(2.f * a);
  return 1.f - 2.f * __builtin_amdgcn_rcpf(e + 1.f);
}

// Build f16 B-fragment-layout copies of the weights.
// Wb[r(32)][nt(3)][kt(50)][lane(64)][8]: r<16 -> W_h rows r*48+nt*16+(l&15); r>=16 -> W_p.
// Wrb[nt(4)][kt(24)][lane(64)][8] for the final projection.
__global__ __launch_bounds__(64) void prep_weights(const float* __restrict__ Wh,
                                                   const float* __restrict__ Wp,
                                                   const float* __restrict__ Wr,
                                                   u16* __restrict__ Wb, u16* __restrict__ Wrb){
  int b = blockIdx.x, l = threadIdx.x;
  int colL = l & 15, kq = l >> 4;
  if (b < 4800){
    int r = b / 150, rem = b % 150;
    int nt = rem / 50, kt = rem % 50;
    int c = nt*16 + colL, k = kt*32 + kq*8;
    const float* src = (r < 16) ? (Wh + (size_t)(r*48 + c)*1600 + k)
                                : (Wp + (size_t)((r-16)*48 + c)*1600 + k);
    f16x8 o;
#pragma unroll
    for (int e = 0; e < 8; ++e) o[e] = (_Float16)src[e];
    *reinterpret_cast<f16x8*>(Wb + ((size_t)b*64 + l)*8) = o;
  } else {
    int b2 = b - 4800;                      // 0..95
    int nt = b2 / 24, kt = b2 % 24;
    int c = nt*16 + colL, k = kt*32 + kq*8;
    const float* src = Wr + (size_t)c*768 + k;
    f16x8 o;
#pragma unroll
    for (int e = 0; e < 8; ++e) o[e] = (_Float16)src[e];
    *reinterpret_cast<f16x8*>(Wrb + ((size_t)b2*64 + l)*8) = o;
  }
}

// grid = 256 blocks: group g = bid&7 (rows g*64..g*64+63), role = bid>>3.
// role<16: h-block (W_h cols role*48..+48, owns hz/hy fp32 state for those cols)
// role>=16: p-block (W_p cols (role-16)*48..+48, publishes hp)
// 256 threads = 4 waves; wave w = m-tile w (16 rows each).
__global__ __launch_bounds__(256, 1) void rnn_main(
    const float* __restrict__ x, const float* __restrict__ bh_g, const float* __restrict__ bp_g,
    const float* __restrict__ br_g, const u16* __restrict__ Wb, const u16* __restrict__ Wrb,
    u16* __restrict__ st, u16* __restrict__ hpB, u32* __restrict__ ctr, float* __restrict__ out)
{
  extern __shared__ u16 smem[];             // weight slice [3][50][64][8] f16 = 153,600 B
  __shared__ int s_dead;

  const int tid  = threadIdx.x;
  const int bid  = blockIdx.x;
  const int g    = bid & 7;
  const int role = bid >> 3;
  const bool is_h = (role < 16);
  const int slice = is_h ? role : (role - 16);
  const int c0   = slice * 48;
  const int l    = tid & 63;
  const int w    = tid >> 6;
  const int colL = l & 15;
  const int kq   = l >> 4;
  const int rowA = w*16 + colL;             // A-frag row within group tile
  const int rowC = w*16 + (l>>4)*4;         // C-frag row base (add e)

  u32* WRp = ctr + (size_t)g*2048;          // 16 slots, stride 32 u32
  u32* HPp = WRp + 512;                     // 16 slots
  u32* RDp = WRp + 1024;                    // 32 slots

  if (tid == 0) s_dead = 0;

  // stage weight slice global -> LDS (153.6 KB)
  {
    const float4* src = reinterpret_cast<const float4*>(Wb + (size_t)role*(3*50*64*8));
    float4* dst = reinterpret_cast<float4*>(smem);
    for (int i = tid; i < 9600; i += 256) dst[i] = src[i];
  }
  __syncthreads();

  float bias[3];
#pragma unroll
  for (int nt = 0; nt < 3; ++nt)
    bias[nt] = (is_h ? bh_g : bp_g)[c0 + nt*16 + colL];

  float hz[3][4] = {}, hy[3][4] = {};
  const f16x8* WlsB = reinterpret_cast<const f16x8*>(smem);

  // wave0-parallel wait: lane i polls slot i; bails to s_dead on timeout (no hangs).
  auto wait_all = [&](u32* arr, int n, u32 tgt){
    if (s_dead) return;
    long spins = 0;
    for (;;){
      bool ok = true;
      if (l < n) ok = (__hip_atomic_load(arr + l*32, __ATOMIC_RELAXED, __HIP_MEMORY_SCOPE_AGENT) >= tgt);
      if (__all(ok)) break;
      __builtin_amdgcn_s_sleep(2);
      if (++spins > 5000000L){ if (l == 0) s_dead = 1; break; }
    }
    __threadfence();                        // acquire: invalidate stale cached data
  };

  const size_t hpbase = (((size_t)(g*16 + slice)*4 + w)*3)*256 + (size_t)l*4;

#pragma unroll 1
  for (int t = 0; t < T_STEPS; ++t){
    if (w == 0) wait_all(WRp, 16, (u32)t);  // tile t published by all 16 h-blocks
    __syncthreads();
    if (s_dead) break;

    // A source: h reads lin plane(0), p reads sq plane(1)
    const u16* sbase = st + ((((size_t)(t&1)*8 + g)*2 + (is_h ? 0 : 1))*64 + rowA)*1536 + kq*8;
    const float* xbase = x + ((size_t)t*BATCH + g*64 + rowA)*64 + kq*8;

    f32x4 acc[3] = {};

    auto lda = [&](int kt)->f16x8{
      if (kt < 2){
        const float4 u = *reinterpret_cast<const float4*>(xbase + kt*32);
        const float4 v = *reinterpret_cast<const float4*>(xbase + kt*32 + 4);
        float f0=u.x,f1=u.y,f2v=u.z,f3=u.w,f4=v.x,f5=v.y,f6=v.z,f7=v.w;
        if (!is_h){ f0*=f0; f1*=f1; f2v*=f2v; f3*=f3; f4*=f4; f5*=f5; f6*=f6; f7*=f7; }
        f16x8 rr;
        rr[0]=(_Float16)f0; rr[1]=(_Float16)f1; rr[2]=(_Float16)f2v; rr[3]=(_Float16)f3;
        rr[4]=(_Float16)f4; rr[5]=(_Float16)f5; rr[6]=(_Float16)f6; rr[7]=(_Float16)f7;
        return rr;
      }
      return *reinterpret_cast<const f16x8*>(sbase + (size_t)(kt-2)*32);
    };

    f16x8 ab[8];
#pragma unroll
    for (int i = 0; i < 8; ++i) ab[i] = lda(i);
#pragma unroll
    for (int kt = 0; kt < 50; ++kt){
      f16x8 a = ab[kt & 7];
      if (kt + 8 < 50) ab[kt & 7] = lda(kt + 8);
#pragma unroll
      for (int nt = 0; nt < 3; ++nt)
        acc[nt] = MFMA16(a, WlsB[(nt*50 + kt)*64 + l], acc[nt]);
    }

    __syncthreads();                        // all tile-t reads by this block are done
    if (tid == 0){
      __threadfence();
      __hip_atomic_store(RDp + role*32, (u32)(t+1), __ATOMIC_RELEASE, __HIP_MEMORY_SCOPE_AGENT);
    }

    if (is_h){
      if (w == 0){
        wait_all(HPp, 16, (u32)(t+1));      // p-blocks published hp for step t
        wait_all(RDp, 32, (u32)t);          // everyone finished reading tile t-1 (buffer reuse)
      }
      __syncthreads();
      if (s_dead) break;

      u16* wlin = st + (((size_t)((t+1)&1)*8 + g)*2 + 0)*64*1536;
      u16* wsq  = wlin + (size_t)64*1536;
#pragma unroll
      for (int nt = 0; nt < 3; ++nt){
        const u16* hp4 = hpB + hpbase + nt*256;
#pragma unroll
        for (int e = 0; e < 4; ++e){
          float hpv = h2f(hp4[e]);
          float hv  = ftanh(acc[nt][e] + bias[nt]);
          hz[nt][e] += DTF * (hv + hpv);
          hy[nt][e] += DTF * hz[nt][e];
          int r = rowC + e;
          int c = c0 + nt*16 + colL;
          float z = hz[nt][e], yv = hy[nt][e];
          wlin[(size_t)r*1536 + c]       = f2h(z);
          wlin[(size_t)r*1536 + 768 + c] = f2h(yv);
          wsq [(size_t)r*1536 + c]       = f2h(z*z);
          wsq [(size_t)r*1536 + 768 + c] = f2h(yv*yv);
        }
      }
      __syncthreads();
      if (tid == 0){
        __threadfence();
        __hip_atomic_store(WRp + slice*32, (u32)(t+1), __ATOMIC_RELEASE, __HIP_MEMORY_SCOPE_AGENT);
      }
    } else {
#pragma unroll
      for (int nt = 0; nt < 3; ++nt){
        u16 o[4];
#pragma unroll
        for (int e = 0; e < 4; ++e) o[e] = f2h(ftanh(acc[nt][e] + bias[nt]));
        *reinterpret_cast<uint2*>(hpB + hpbase + nt*256) = *reinterpret_cast<const uint2*>(o);
      }
      __syncthreads();
      if (tid == 0){
        __threadfence();
        __hip_atomic_store(HPp + slice*32, (u32)(t+1), __ATOMIC_RELEASE, __HIP_MEMORY_SCOPE_AGENT);
      }
    }
  }

  // final projection: out = hy @ W_r^T + b_r, done by role-0 block of each group
  if (role == 0){
    if (w == 0) wait_all(WRp, 16, (u32)T_STEPS);
    __syncthreads();
    if (!s_dead){
      // tile 512 lives in buf 0, lin plane, hy section at k offset 768
      const u16* hybase = st + (((size_t)g*2 + 0)*64 + rowA)*1536 + 768 + kq*8;
      const f16x8* Wr8 = reinterpret_cast<const f16x8*>(Wrb);
      f32x4 oc[4] = {};
#pragma unroll
      for (int kt = 0; kt < 24; ++kt){
        f16x8 a = *reinterpret_cast<const f16x8*>(hybase + (size_t)kt*32);
#pragma unroll
        for (int nt = 0; nt < 4; ++nt)
          oc[nt] = MFMA16(a, Wr8[(nt*24 + kt)*64 + l], oc[nt]);
      }
#pragma unroll
      for (int nt = 0; nt < 4; ++nt){
        float bb = br_g[nt*16 + colL];
#pragma unroll
        for (int e = 0; e < 4; ++e){
          int r = g*64 + rowC + e;
          out[(size_t)r*64 + nt*16 + colL] = oc[nt][e] + bb;
        }
      }
    }
  }
}

extern "C" void kernel_launch(void* const* d_in, const int* in_sizes, int n_in,
                              void* d_out, int out_size, void* d_ws, size_t ws_size,
                              hipStream_t stream) {
  const float* x  = (const float*)d_in[0];
  const float* Wh = (const float*)d_in[1];
  const float* bh = (const float*)d_in[2];
  const float* Wp = (const float*)d_in[3];
  const float* bp = (const float*)d_in[4];
  const float* Wr = (const float*)d_in[5];
  const float* br = (const float*)d_in[6];
  float* out = (float*)d_out;

  if (ws_size < (size_t)WS_NEED) return;    // loud failure: output stays zero
  char* ws = (char*)d_ws;

  u16* Wb  = (u16*)(ws + WB_OFF);
  u16* Wrb = (u16*)(ws + WRB_OFF);
  u16* st  = (u16*)(ws + ST_OFF);
  u16* hpB = (u16*)(ws + HP_OFF);
  u32* ctr = (u32*)(ws + CTR_OFF);

  hipMemsetAsync(ws + CTR_OFF, 0, CTR_SZ, stream);   // progress counters
  hipMemsetAsync(ws + ST_OFF,  0, ST_SZ,  stream);   // zero initial state tiles

  prep_weights<<<4896, 64, 0, stream>>>(Wh, Wp, Wr, Wb, Wrb);

  (void)hipFuncSetAttribute(reinterpret_cast<const void*>(rnn_main),
                            hipFuncAttributeMaxDynamicSharedMemorySize, 153600);
  rnn_main<<<256, 256, 153600, stream>>>(x, bh, bp, br, Wb, Wrb, st, hpB, ctr, out);
}

// Round 2
// 15252.719 us; speedup vs baseline: 1.4585x; 1.4585x over previous
//
#include <hip/hip_runtime.h>
#include <hip/hip_fp16.h>

typedef _Float16 f16x8 __attribute__((ext_vector_type(8)));
typedef float f32x4 __attribute__((ext_vector_type(4)));
typedef unsigned short u16;
typedef unsigned int u32;

#define T_STEPS 512
#define BATCH   512
#define DTF     0.01f

// workspace layout (bytes)
#define CTR_OFF 0
#define CTR_SZ  131072                      // slot counters + WR/HP flags
#define WB_OFF  (CTR_OFF + CTR_SZ)
#define WB_SZ   (32*3*50*64*8*2)            // 4,915,200  W_h/W_p f16 B-frag layout
#define WRB_OFF (WB_OFF + WB_SZ)
#define WRB_SZ  (4*24*64*8*2)               // 98,304     W_r f16 B-frag layout
#define ST_OFF  (WRB_OFF + WRB_SZ)
#define ST_SZ   (2*512*1536*2)              // 3,145,728  state [buf][512 rows][hz 768 | hy 768] f16
#define HP_OFF  (ST_OFF + ST_SZ)
#define HP_SZ   (2*8*16*4*3*64*4*2)         // 1,572,864  hp frags [buf][g][slice][w][nt][lane][4]
#define WS_NEED (HP_OFF + HP_SZ)

#define MFMA16(a,b,c) __builtin_amdgcn_mfma_f32_16x16x32_f16((a),(b),(c),0,0,0)

__device__ __forceinline__ u16 f2h(float f){ _Float16 h = (_Float16)f; return *reinterpret_cast<u16*>(&h); }
__device__ __forceinline__ float h2f(u16 u){ _Float16 h = *reinterpret_cast<_Float16*>(&u); return (float)h; }

__device__ __forceinline__ float ftanh(float x){
  float a = fminf(fmaxf(x, -12.f), 12.f);
  float e = __expf(2.f * a);
  return 1.f - 2.f * __builtin_amdgcn_rcpf(e + 1.f);
}

// Wb[r(32)][nt(3)][kt(50)][lane(64)][8]: r<16 -> W_h rows r*48+nt*16+(l&15); r>=16 -> W_p.
// Wrb[nt(4)][kt(24)][lane(64)][8] for the final projection.
__global__ __launch_bounds__(64) void prep_weights(const float* __restrict__ Wh,
                                                   const float* __restrict__ Wp,
                                                   const float* __restrict__ Wr,
                                                   u16* __restrict__ Wb, u16* __restrict__ Wrb){
  int b = blockIdx.x, l = threadIdx.x;
  int colL = l & 15, kq = l >> 4;
  if (b < 4800){
    int r = b / 150, rem = b % 150;
    int nt = rem / 50, kt = rem % 50;
    int c = nt*16 + colL, k = kt*32 + kq*8;
    const float* src = (r < 16) ? (Wh + (size_t)(r*48 + c)*1600 + k)
                                : (Wp + (size_t)((r-16)*48 + c)*1600 + k);
    f16x8 o;
#pragma unroll
    for (int e = 0; e < 8; ++e) o[e] = (_Float16)src[e];
    *reinterpret_cast<f16x8*>(Wb + ((size_t)b*64 + l)*8) = o;
  } else {
    int b2 = b - 4800;                      // 0..95
    int nt = b2 / 24, kt = b2 % 24;
    int c = nt*16 + colL, k = kt*32 + kq*8;
    const float* src = Wr + (size_t)c*768 + k;
    f16x8 o;
#pragma unroll
    for (int e = 0; e < 8; ++e) o[e] = (_Float16)src[e];
    *reinterpret_cast<f16x8*>(Wrb + ((size_t)b2*64 + l)*8) = o;
  }
}

// grid = 256 blocks x 256 threads. Group = PHYSICAL XCD (via HW_REG_XCC_ID),
// slot within XCD via atomicAdd: 32 blocks/XCD guaranteed (1 block/CU by LDS).
// slot<16: h-block (W_h cols slot*48, owns fp32 hz/hy); slot>=16: p-block (W_p).
// All group traffic is intra-XCD => L2 is the coherence point; releases need
// only vmcnt(0)+flag (no wbl2), acquires need only L1 inv.
__global__ __launch_bounds__(256, 1) void rnn_main(
    const float* __restrict__ x, const float* __restrict__ bh_g, const float* __restrict__ bp_g,
    const float* __restrict__ br_g, const u16* __restrict__ Wb, const u16* __restrict__ Wrb,
    u16* __restrict__ st, u16* __restrict__ hpB, u32* __restrict__ ctr, float* __restrict__ out)
{
  extern __shared__ u16 smem[];             // weight slice [3][50][64][8] f16 = 153,600 B
  __shared__ int s_dead, s_slot, s_xcd;

  const int tid = threadIdx.x;
  if (tid == 0){
    s_dead = 0;
    u32 xcd;
    asm volatile("s_getreg_b32 %0, hwreg(HW_REG_XCC_ID)" : "=s"(xcd));
    xcd &= 7u;
    s_xcd  = (int)xcd;
    s_slot = (int)atomicAdd(ctr + xcd, 1u); // device-scope, ctr pre-zeroed
  }
  __syncthreads();
  const int g = s_xcd;
  const int s = s_slot;
  if (s >= 32) return;                      // impossible unless XCC assumptions break

  const bool is_h = (s < 16);
  const int slice = is_h ? s : (s - 16);
  const int c0   = slice * 48;
  const int l    = tid & 63;
  const int w    = tid >> 6;
  const int colL = l & 15;
  const int kq   = l >> 4;
  const int rowA = w*16 + colL;             // A-frag row within group tile (M=64, wave=mtile)
  const int rowC = w*16 + (l>>4)*4;         // C-frag row base (add e)

  u32* WRb = ctr + 1024 + (size_t)g*2048;   // 16 h flags, stride 32 u32 (128B)
  u32* HPb = WRb + 1024;                    // 16 p flags

  // stage this slot's weight slice global -> LDS (153.6 KB)
  {
    const float4* srcw = reinterpret_cast<const float4*>(Wb + (size_t)s*(3*50*64*8));
    float4* dst = reinterpret_cast<float4*>(smem);
    for (int i = tid; i < 9600; i += 256) dst[i] = srcw[i];
  }
  __syncthreads();

  float bias[3];
#pragma unroll
  for (int nt = 0; nt < 3; ++nt)
    bias[nt] = (is_h ? bh_g : bp_g)[c0 + nt*16 + colL];

  float hz[3][4] = {}, hy[3][4] = {};
  const f16x8* WlsB = reinterpret_cast<const f16x8*>(smem);

  // wave0-parallel wait: lane i<16 polls flag i against per-lane target; timeout bails.
  auto wait_all = [&](u32* arr, u32 tgt){
    if (s_dead) return;
    long spins = 0;
    for (;;){
      bool ok = true;
      if (l < 16) ok = (__hip_atomic_load(arr + l*32, __ATOMIC_RELAXED, __HIP_MEMORY_SCOPE_AGENT) >= tgt);
      if (__all(ok)) break;
      __builtin_amdgcn_s_sleep(2);
      if (++spins > 2000000L){ if (l == 0) s_dead = 1; break; }
    }
  };

  const size_t hpbase = ((((size_t)0*8 + g)*16 + slice)*4 + w)*3*256 + (size_t)l*4; // buf0 base
  const size_t hpstride = (size_t)8*16*4*3*256;                                     // buf stride (u16)

#pragma unroll 1
  for (int t = 0; t < T_STEPS; ++t){
    if (w == 0) wait_all(WRb, (u32)t);      // tile t published by all 16 h-blocks
    __syncthreads();
    if (s_dead) break;
    __builtin_amdgcn_fence(__ATOMIC_ACQUIRE, "agent");   // L1 inv; tile t now visible

    // A source: lin plane only; p squares in-register
    const u16* sbase = st + (((size_t)(t&1)*512) + g*64 + rowA)*1536 + kq*8;
    const float* xb  = x + ((size_t)t*BATCH + g*64 + rowA)*64 + kq*8;

    f32x4 acc[3] = {};

    // i = pipeline index; i<48 -> state kt=i+2 (L2-warm), i>=48 -> x kt=i-48 (HBM-cold, issued late)
    auto lda = [&](int i)->f16x8{
      if (i < 48){
        f16x8 r = *reinterpret_cast<const f16x8*>(sbase + (size_t)i*32);
        if (!is_h) r = r*r;                 // packed f16 square
        return r;
      }
      const float4 u = *reinterpret_cast<const float4*>(xb + (i-48)*32);
      const float4 v = *reinterpret_cast<const float4*>(xb + (i-48)*32 + 4);
      f16x8 r;
      if (is_h){
        r[0]=(_Float16)u.x; r[1]=(_Float16)u.y; r[2]=(_Float16)u.z; r[3]=(_Float16)u.w;
        r[4]=(_Float16)v.x; r[5]=(_Float16)v.y; r[6]=(_Float16)v.z; r[7]=(_Float16)v.w;
      } else {
        r[0]=(_Float16)(u.x*u.x); r[1]=(_Float16)(u.y*u.y); r[2]=(_Float16)(u.z*u.z); r[3]=(_Float16)(u.w*u.w);
        r[4]=(_Float16)(v.x*v.x); r[5]=(_Float16)(v.y*v.y); r[6]=(_Float16)(v.z*v.z); r[7]=(_Float16)(v.w*v.w);
      }
      return r;
    };

    f16x8 ab[8];
#pragma unroll
    for (int i = 0; i < 8; ++i) ab[i] = lda(i);
#pragma unroll
    for (int i = 0; i < 50; ++i){
      f16x8 a = ab[i & 7];
      if (i + 8 < 50) ab[i & 7] = lda(i + 8);
      const int kt = (i < 48) ? (i + 2) : (i - 48);
#pragma unroll
      for (int nt = 0; nt < 3; ++nt)
        acc[nt] = MFMA16(a, WlsB[(nt*50 + kt)*64 + l], acc[nt]);
    }

    if (is_h){
      // need: own hp(t) (flag slice >= t+1) AND all p done reading tile t-1 (flags >= t)
      if (w == 0) wait_all(HPb, (l == slice) ? (u32)(t+1) : (u32)t);
      __syncthreads();
      if (s_dead) break;
      __builtin_amdgcn_fence(__ATOMIC_ACQUIRE, "agent"); // see p's hp frags

      const u16* hp4 = hpB + hpbase + (size_t)(t&1)*hpstride;
      u16* wt = st + ((size_t)((t+1)&1)*512 + g*64)*1536;
#pragma unroll
      for (int nt = 0; nt < 3; ++nt){
#pragma unroll
        for (int e = 0; e < 4; ++e){
          float hpv = h2f(hp4[nt*256 + e]);
          float hv  = ftanh(acc[nt][e] + bias[nt]);
          hz[nt][e] += DTF * (hv + hpv);
          hy[nt][e] += DTF * hz[nt][e];
          int r = rowC + e;
          int c = c0 + nt*16 + colL;
          wt[(size_t)r*1536 + c]       = f2h(hz[nt][e]);
          wt[(size_t)r*1536 + 768 + c] = f2h(hy[nt][e]);
        }
      }
      asm volatile("s_waitcnt vmcnt(0)" ::: "memory");   // stores visible in XCD L2
      __syncthreads();
      if (tid == 0)
        __hip_atomic_store(WRb + slice*32, (u32)(t+1), __ATOMIC_RELAXED, __HIP_MEMORY_SCOPE_AGENT);
    } else {
      u16* hpw = hpB + hpbase + (size_t)(t&1)*hpstride;
#pragma unroll
      for (int nt = 0; nt < 3; ++nt){
        u16 o[4];
#pragma unroll
        for (int e = 0; e < 4; ++e) o[e] = f2h(ftanh(acc[nt][e] + bias[nt]));
        *reinterpret_cast<uint2*>(hpw + nt*256) = *reinterpret_cast<const uint2*>(o);
      }
      asm volatile("s_waitcnt vmcnt(0)" ::: "memory");
      __syncthreads();
      if (tid == 0)
        __hip_atomic_store(HPb + slice*32, (u32)(t+1), __ATOMIC_RELAXED, __HIP_MEMORY_SCOPE_AGENT);
    }
  }

  // final projection: out = hy @ W_r^T + b_r, by h-slice0 block of each group
  if (is_h && slice == 0 && !s_dead){
    if (w == 0) wait_all(WRb, (u32)T_STEPS);
    __syncthreads();
    if (!s_dead){
      __builtin_amdgcn_fence(__ATOMIC_ACQUIRE, "agent");
      // tile 512 in buf0; hy section at col offset 768
      const u16* hyb = st + ((size_t)g*64 + rowA)*1536 + 768 + kq*8;
      const f16x8* Wr8 = reinterpret_cast<const f16x8*>(Wrb);
      f32x4 oc[4] = {};
#pragma unroll
      for (int kt = 0; kt < 24; ++kt){
        f16x8 a = *reinterpret_cast<const f16x8*>(hyb + (size_t)kt*32);
#pragma unroll
        for (int nt = 0; nt < 4; ++nt)
          oc[nt] = MFMA16(a, Wr8[(nt*24 + kt)*64 + l], oc[nt]);
      }
#pragma unroll
      for (int nt = 0; nt < 4; ++nt){
        float bb = br_g[nt*16 + colL];
#pragma unroll
        for (int e = 0; e < 4; ++e)
          out[(size_t)(g*64 + rowC + e)*64 + nt*16 + colL] = oc[nt][e] + bb;
      }
    }
  }
}

extern "C" void kernel_launch(void* const* d_in, const int* in_sizes, int n_in,
                              void* d_out, int out_size, void* d_ws, size_t ws_size,
                              hipStream_t stream) {
  const float* x  = (const float*)d_in[0];
  const float* Wh = (const float*)d_in[1];
  const float* bh = (const float*)d_in[2];
  const float* Wp = (const float*)d_in[3];
  const float* bp = (const float*)d_in[4];
  const float* Wr = (const float*)d_in[5];
  const float* br = (const float*)d_in[6];
  float* out = (float*)d_out;

  if (ws_size < (size_t)WS_NEED) return;    // loud failure: output stays zero
  char* ws = (char*)d_ws;

  u16* Wb  = (u16*)(ws + WB_OFF);
  u16* Wrb = (u16*)(ws + WRB_OFF);
  u16* st  = (u16*)(ws + ST_OFF);
  u16* hpB = (u16*)(ws + HP_OFF);
  u32* ctr = (u32*)(ws + CTR_OFF);

  hipMemsetAsync(ws + CTR_OFF, 0, CTR_SZ, stream);   // slot counters + flags
  hipMemsetAsync(ws + ST_OFF,  0, ST_SZ,  stream);   // zero initial state tiles

  prep_weights<<<4896, 64, 0, stream>>>(Wh, Wp, Wr, Wb, Wrb);

  (void)hipFuncSetAttribute(reinterpret_cast<const void*>(rnn_main),
                            hipFuncAttributeMaxDynamicSharedMemorySize, 153600);
  rnn_main<<<256, 256, 153600, stream>>>(x, bh, bp, br, Wb, Wrb, st, hpB, ctr, out);
}

// Round 3
// 10302.567 us; speedup vs baseline: 2.1593x; 1.4805x over previous
//
#include <hip/hip_runtime.h>
#include <hip/hip_fp16.h>

typedef _Float16 f16x8 __attribute__((ext_vector_type(8)));
typedef float f32x4 __attribute__((ext_vector_type(4)));
typedef unsigned short u16;
typedef unsigned int u32;

#define T_STEPS 512
#define BATCH   512
#define DTF     0.01f

// workspace layout (bytes)
#define CTR_OFF 0
#define CTR_SZ  131072                      // slot counters + WR/HP flags
#define WB_OFF  (CTR_OFF + CTR_SZ)
#define WB_SZ   (32*3*50*64*8*2)            // 4,915,200  W_h/W_p f16 B-frag layout
#define WRB_OFF (WB_OFF + WB_SZ)
#define WRB_SZ  (4*24*64*8*2)               // 98,304     W_r f16 B-frag layout
#define ST_OFF  (WRB_OFF + WRB_SZ)
#define ST_SZ   (2*512*1536*2)              // 3,145,728  state [buf][512 rows][hz 768 | hy 768] f16
#define HP_OFF  (ST_OFF + ST_SZ)
#define HP_SZ   (2*8*16*4*3*64*4*2)         // 1,572,864  hp frags [buf][g][slice][w][nt][lane][4]
#define WS_NEED (HP_OFF + HP_SZ)

#define MFMA16(a,b,c) __builtin_amdgcn_mfma_f32_16x16x32_f16((a),(b),(c),0,0,0)

// Acquire for intra-XCD sharing: L2 is the coherence point (all peers on this
// XCD by construction), L1 is write-through => only L1 can be stale. Invalidate
// L1 ONLY (sc0) — the agent-scope fence's L2 invalidate was the round-2 cost.
#define ACQUIRE_L1() asm volatile("s_waitcnt vmcnt(0)\n\tbuffer_inv sc0" ::: "memory")

__device__ __forceinline__ u16 f2h(float f){ _Float16 h = (_Float16)f; return *reinterpret_cast<u16*>(&h); }
__device__ __forceinline__ float h2f(u16 u){ _Float16 h = *reinterpret_cast<_Float16*>(&u); return (float)h; }

__device__ __forceinline__ float ftanh(float x){
  float a = fminf(fmaxf(x, -12.f), 12.f);
  float e = __expf(2.f * a);
  return 1.f - 2.f * __builtin_amdgcn_rcpf(e + 1.f);
}

// Wb[r(32)][nt(3)][kt(50)][lane(64)][8]: r<16 -> W_h rows r*48+nt*16+(l&15); r>=16 -> W_p.
// Wrb[nt(4)][kt(24)][lane(64)][8] for the final projection.
__global__ __launch_bounds__(64) void prep_weights(const float* __restrict__ Wh,
                                                   const float* __restrict__ Wp,
                                                   const float* __restrict__ Wr,
                                                   u16* __restrict__ Wb, u16* __restrict__ Wrb){
  int b = blockIdx.x, l = threadIdx.x;
  int colL = l & 15, kq = l >> 4;
  if (b < 4800){
    int r = b / 150, rem = b % 150;
    int nt = rem / 50, kt = rem % 50;
    int c = nt*16 + colL, k = kt*32 + kq*8;
    const float* src = (r < 16) ? (Wh + (size_t)(r*48 + c)*1600 + k)
                                : (Wp + (size_t)((r-16)*48 + c)*1600 + k);
    f16x8 o;
#pragma unroll
    for (int e = 0; e < 8; ++e) o[e] = (_Float16)src[e];
    *reinterpret_cast<f16x8*>(Wb + ((size_t)b*64 + l)*8) = o;
  } else {
    int b2 = b - 4800;                      // 0..95
    int nt = b2 / 24, kt = b2 % 24;
    int c = nt*16 + colL, k = kt*32 + kq*8;
    const float* src = Wr + (size_t)c*768 + k;
    f16x8 o;
#pragma unroll
    for (int e = 0; e < 8; ++e) o[e] = (_Float16)src[e];
    *reinterpret_cast<f16x8*>(Wrb + ((size_t)b2*64 + l)*8) = o;
  }
}

// grid = 256 blocks x 256 threads. Group = PHYSICAL XCD (via HW_REG_XCC_ID),
// slot within XCD via atomicAdd: 32 blocks/XCD guaranteed (1 block/CU by LDS).
// slot<16: h-block (W_h cols slot*48, owns fp32 hz/hy); slot>=16: p-block (W_p).
__global__ __launch_bounds__(256, 1) void rnn_main(
    const float* __restrict__ x, const float* __restrict__ bh_g, const float* __restrict__ bp_g,
    const float* __restrict__ br_g, const u16* __restrict__ Wb, const u16* __restrict__ Wrb,
    u16* __restrict__ st, u16* __restrict__ hpB, u32* __restrict__ ctr, float* __restrict__ out)
{
  extern __shared__ u16 smem[];             // weight slice [3][50][64][8] f16 = 153,600 B
  __shared__ int s_dead, s_slot, s_xcd;

  const int tid = threadIdx.x;
  if (tid == 0){
    s_dead = 0;
    u32 xcd;
    asm volatile("s_getreg_b32 %0, hwreg(HW_REG_XCC_ID)" : "=s"(xcd));
    xcd &= 7u;
    s_xcd  = (int)xcd;
    s_slot = (int)atomicAdd(ctr + xcd, 1u); // device-scope, ctr pre-zeroed
  }
  __syncthreads();
  const int g = s_xcd;
  const int s = s_slot;
  if (s >= 32) return;                      // impossible unless XCC assumptions break

  const bool is_h = (s < 16);
  const int slice = is_h ? s : (s - 16);
  const int c0   = slice * 48;
  const int l    = tid & 63;
  const int w    = tid >> 6;
  const int colL = l & 15;
  const int kq   = l >> 4;
  const int rowA = w*16 + colL;             // A-frag row within group tile (M=64, wave=mtile)
  const int rowC = w*16 + (l>>4)*4;         // C-frag row base (add e)

  u32* WRb = ctr + 1024 + (size_t)g*2048;   // 16 h flags, stride 32 u32 (128B)
  u32* HPb = WRb + 1024;                    // 16 p flags

  // stage this slot's weight slice global -> LDS (153.6 KB)
  {
    const float4* srcw = reinterpret_cast<const float4*>(Wb + (size_t)s*(3*50*64*8));
    float4* dst = reinterpret_cast<float4*>(smem);
    for (int i = tid; i < 9600; i += 256) dst[i] = srcw[i];
  }
  __syncthreads();

  float bias[3];
#pragma unroll
  for (int nt = 0; nt < 3; ++nt)
    bias[nt] = (is_h ? bh_g : bp_g)[c0 + nt*16 + colL];

  float hz[3][4] = {}, hy[3][4] = {};
  const f16x8* WlsB = reinterpret_cast<const f16x8*>(smem);

  // wave0-parallel wait: lane i<16 polls flag i against per-lane target; timeout bails.
  auto wait_all = [&](u32* arr, u32 tgt){
    if (s_dead) return;
    long spins = 0;
    for (;;){
      bool ok = true;
      if (l < 16) ok = (__hip_atomic_load(arr + l*32, __ATOMIC_RELAXED, __HIP_MEMORY_SCOPE_AGENT) >= tgt);
      if (__all(ok)) break;
      __builtin_amdgcn_s_sleep(1);
      if (++spins > 4000000L){ if (l == 0) s_dead = 1; break; }
    }
  };

  const size_t hpbase = ((((size_t)0*8 + g)*16 + slice)*4 + w)*3*256 + (size_t)l*4; // buf0 base
  const size_t hpstride = (size_t)8*16*4*3*256;                                     // buf stride (u16)

#pragma unroll 1
  for (int t = 0; t < T_STEPS; ++t){
    if (w == 0) wait_all(WRb, (u32)t);      // tile t published by all 16 h-blocks
    __syncthreads();
    if (s_dead) break;
    ACQUIRE_L1();                           // tile t visible (L2 coherent, L1 inv)

    // A source: lin plane only; p squares in-register
    const u16* sbase = st + (((size_t)(t&1)*512) + g*64 + rowA)*1536 + kq*8;
    const float* xb  = x + ((size_t)t*BATCH + g*64 + rowA)*64 + kq*8;

    f32x4 acc[3] = {};

    // i = pipeline index; i<48 -> state kt=i+2 (L2-warm), i>=48 -> x kt=i-48 (HBM-cold, issued late)
    auto lda = [&](int i)->f16x8{
      if (i < 48){
        f16x8 r = *reinterpret_cast<const f16x8*>(sbase + (size_t)i*32);
        if (!is_h) r = r*r;                 // packed f16 square
        return r;
      }
      const float4 u = *reinterpret_cast<const float4*>(xb + (i-48)*32);
      const float4 v = *reinterpret_cast<const float4*>(xb + (i-48)*32 + 4);
      f16x8 r;
      if (is_h){
        r[0]=(_Float16)u.x; r[1]=(_Float16)u.y; r[2]=(_Float16)u.z; r[3]=(_Float16)u.w;
        r[4]=(_Float16)v.x; r[5]=(_Float16)v.y; r[6]=(_Float16)v.z; r[7]=(_Float16)v.w;
      } else {
        r[0]=(_Float16)(u.x*u.x); r[1]=(_Float16)(u.y*u.y); r[2]=(_Float16)(u.z*u.z); r[3]=(_Float16)(u.w*u.w);
        r[4]=(_Float16)(v.x*v.x); r[5]=(_Float16)(v.y*v.y); r[6]=(_Float16)(v.z*v.z); r[7]=(_Float16)(v.w*v.w);
      }
      return r;
    };

    f16x8 ab[8];
#pragma unroll
    for (int i = 0; i < 8; ++i) ab[i] = lda(i);
#pragma unroll
    for (int i = 0; i < 50; ++i){
      f16x8 a = ab[i & 7];
      if (i + 8 < 50) ab[i & 7] = lda(i + 8);
      const int kt = (i < 48) ? (i + 2) : (i - 48);
#pragma unroll
      for (int nt = 0; nt < 3; ++nt)
        acc[nt] = MFMA16(a, WlsB[(nt*50 + kt)*64 + l], acc[nt]);
    }

    if (is_h){
      // need: own hp(t) (flag slice >= t+1) AND all p done reading tile t-1 (flags >= t)
      if (w == 0) wait_all(HPb, (l == slice) ? (u32)(t+1) : (u32)t);
      __syncthreads();
      if (s_dead) break;
      ACQUIRE_L1();                         // p's hp frags visible

      const u16* hp4 = hpB + hpbase + (size_t)(t&1)*hpstride;
      u16* wt = st + ((size_t)((t+1)&1)*512 + g*64)*1536;
#pragma unroll
      for (int nt = 0; nt < 3; ++nt){
#pragma unroll
        for (int e = 0; e < 4; ++e){
          float hpv = h2f(hp4[nt*256 + e]);
          float hv  = ftanh(acc[nt][e] + bias[nt]);
          hz[nt][e] += DTF * (hv + hpv);
          hy[nt][e] += DTF * hz[nt][e];
          int r = rowC + e;
          int c = c0 + nt*16 + colL;
          wt[(size_t)r*1536 + c]       = f2h(hz[nt][e]);
          wt[(size_t)r*1536 + 768 + c] = f2h(hy[nt][e]);
        }
      }
      asm volatile("s_waitcnt vmcnt(0)" ::: "memory");   // stores visible in XCD L2
      __syncthreads();
      if (tid == 0)
        __hip_atomic_store(WRb + slice*32, (u32)(t+1), __ATOMIC_RELAXED, __HIP_MEMORY_SCOPE_AGENT);
    } else {
      u16* hpw = hpB + hpbase + (size_t)(t&1)*hpstride;
#pragma unroll
      for (int nt = 0; nt < 3; ++nt){
        u16 o[4];
#pragma unroll
        for (int e = 0; e < 4; ++e) o[e] = f2h(ftanh(acc[nt][e] + bias[nt]));
        *reinterpret_cast<uint2*>(hpw + nt*256) = *reinterpret_cast<const uint2*>(o);
      }
      asm volatile("s_waitcnt vmcnt(0)" ::: "memory");
      __syncthreads();
      if (tid == 0)
        __hip_atomic_store(HPb + slice*32, (u32)(t+1), __ATOMIC_RELAXED, __HIP_MEMORY_SCOPE_AGENT);
    }
  }

  // final projection: out = hy @ W_r^T + b_r, by h-slice0 block of each group
  if (is_h && slice == 0 && !s_dead){
    if (w == 0) wait_all(WRb, (u32)T_STEPS);
    __syncthreads();
    if (!s_dead){
      ACQUIRE_L1();
      // tile 512 in buf0; hy section at col offset 768
      const u16* hyb = st + ((size_t)g*64 + rowA)*1536 + 768 + kq*8;
      const f16x8* Wr8 = reinterpret_cast<const f16x8*>(Wrb);
      f32x4 oc[4] = {};
#pragma unroll
      for (int kt = 0; kt < 24; ++kt){
        f16x8 a = *reinterpret_cast<const f16x8*>(hyb + (size_t)kt*32);
#pragma unroll
        for (int nt = 0; nt < 4; ++nt)
          oc[nt] = MFMA16(a, Wr8[(nt*24 + kt)*64 + l], oc[nt]);
      }
#pragma unroll
      for (int nt = 0; nt < 4; ++nt){
        float bb = br_g[nt*16 + colL];
#pragma unroll
        for (int e = 0; e < 4; ++e)
          out[(size_t)(g*64 + rowC + e)*64 + nt*16 + colL] = oc[nt][e] + bb;
      }
    }
  }
}

extern "C" void kernel_launch(void* const* d_in, const int* in_sizes, int n_in,
                              void* d_out, int out_size, void* d_ws, size_t ws_size,
                              hipStream_t stream) {
  const float* x  = (const float*)d_in[0];
  const float* Wh = (const float*)d_in[1];
  const float* bh = (const float*)d_in[2];
  const float* Wp = (const float*)d_in[3];
  const float* bp = (const float*)d_in[4];
  const float* Wr = (const float*)d_in[5];
  const float* br = (const float*)d_in[6];
  float* out = (float*)d_out;

  if (ws_size < (size_t)WS_NEED) return;    // loud failure: output stays zero
  char* ws = (char*)d_ws;

  u16* Wb  = (u16*)(ws + WB_OFF);
  u16* Wrb = (u16*)(ws + WRB_OFF);
  u16* st  = (u16*)(ws + ST_OFF);
  u16* hpB = (u16*)(ws + HP_OFF);
  u32* ctr = (u32*)(ws + CTR_OFF);

  hipMemsetAsync(ws + CTR_OFF, 0, CTR_SZ, stream);   // slot counters + flags
  hipMemsetAsync(ws + ST_OFF,  0, ST_SZ,  stream);   // zero initial state tiles

  prep_weights<<<4896, 64, 0, stream>>>(Wh, Wp, Wr, Wb, Wrb);

  (void)hipFuncSetAttribute(reinterpret_cast<const void*>(rnn_main),
                            hipFuncAttributeMaxDynamicSharedMemorySize, 153600);
  rnn_main<<<256, 256, 153600, stream>>>(x, bh, bp, br, Wb, Wrb, st, hpB, ctr, out);
}